// Round 1
// baseline (11.150 us; speedup 1.0000x reference)
//
#include <hip/hip_runtime.h>

constexpr int SEQ    = 8192;
constexpr int VOCAB  = 10;
constexpr int D_EMB  = 3;
constexpr int D_HEAD = 4;
constexpr int BLOCK  = 256;
constexpr int GRID   = SEQ / BLOCK;   // 32 blocks, 1 output row per thread

__global__ __launch_bounds__(BLOCK) void fused_tok_attn(
    const int*   __restrict__ x,
    const float* __restrict__ emb_table,
    const float* __restrict__ Wq, const float* __restrict__ bq,
    const float* __restrict__ Wk, const float* __restrict__ bk,
    const float* __restrict__ Wv, const float* __restrict__ bv,
    float*       __restrict__ out)
{
    __shared__ int    hist[VOCAB];
    __shared__ float  qt[VOCAB][D_HEAD];
    __shared__ float  kt[VOCAB][D_HEAD];
    __shared__ float  vt[VOCAB][D_HEAD];
    __shared__ float4 Otab[VOCAB];

    const int tid = threadIdx.x;

    // ---- Phase 1: full-sequence histogram (redundant per block; 32 KB, L2-hot) ----
    int cnt[VOCAB];
#pragma unroll
    for (int t = 0; t < VOCAB; ++t) cnt[t] = 0;

    const int4* x4 = reinterpret_cast<const int4*>(x);
#pragma unroll
    for (int i = 0; i < SEQ / (BLOCK * 4); ++i) {     // 8 iters, 16 B/lane coalesced
        const int4 tk = x4[i * BLOCK + tid];
#pragma unroll
        for (int t = 0; t < VOCAB; ++t) {             // compile-time index -> registers
            cnt[t] += (tk.x == t) + (tk.y == t) + (tk.z == t) + (tk.w == t);
        }
    }
    // wave64 butterfly-reduce each counter down to lane 0
#pragma unroll
    for (int t = 0; t < VOCAB; ++t) {
        int v = cnt[t];
#pragma unroll
        for (int off = 32; off > 0; off >>= 1) v += __shfl_down(v, off);
        cnt[t] = v;
    }
    if (tid < VOCAB) hist[tid] = 0;
    __syncthreads();
    if ((tid & 63) == 0) {                            // lane 0 of each of 4 waves
#pragma unroll
        for (int t = 0; t < VOCAB; ++t) atomicAdd(&hist[t], cnt[t]);
    }

    // ---- Phase 2: q/k/v type tables, one (type,dim) pair per lane (40 lanes) ----
    if (tid < VOCAB * D_HEAD) {
        const int t = tid >> 2, d = tid & 3;
        const float e0 = emb_table[t * D_EMB + 0];
        const float e1 = emb_table[t * D_EMB + 1];
        const float e2 = emb_table[t * D_EMB + 2];
        qt[t][d] = fmaf(e0, Wq[0 * D_HEAD + d],
                   fmaf(e1, Wq[1 * D_HEAD + d],
                   fmaf(e2, Wq[2 * D_HEAD + d], bq[d])));
        kt[t][d] = fmaf(e0, Wk[0 * D_HEAD + d],
                   fmaf(e1, Wk[1 * D_HEAD + d],
                   fmaf(e2, Wk[2 * D_HEAD + d], bk[d])));
        vt[t][d] = fmaf(e0, Wv[0 * D_HEAD + d],
                   fmaf(e1, Wv[1 * D_HEAD + d],
                   fmaf(e2, Wv[2 * D_HEAD + d], bv[d])));
    }
    __syncthreads();

    // ---- Phase 3: per-type softmax-attention output row (10 lanes) ----
    if (tid < VOCAB) {
        const int a = tid;
        float s[VOCAB];
        float m = -3.0e38f;
#pragma unroll
        for (int t = 0; t < VOCAB; ++t) {
            const float sv = 0.5f * (qt[a][0] * kt[t][0] + qt[a][1] * kt[t][1] +
                                     qt[a][2] * kt[t][2] + qt[a][3] * kt[t][3]);
            s[t] = sv;                                 // unrolled -> registers
            m = fmaxf(m, sv);
        }
        float denom = 0.f, o0 = 0.f, o1 = 0.f, o2 = 0.f, o3 = 0.f;
#pragma unroll
        for (int t = 0; t < VOCAB; ++t) {
            const float w = (float)hist[t] * __expf(s[t] - m);  // s-m <= 0: no overflow
            denom += w;
            o0 = fmaf(w, vt[t][0], o0);
            o1 = fmaf(w, vt[t][1], o1);
            o2 = fmaf(w, vt[t][2], o2);
            o3 = fmaf(w, vt[t][3], o3);
        }
        const float inv = 1.0f / denom;
        Otab[a] = make_float4(o0 * inv, o1 * inv, o2 * inv, o3 * inv);
    }
    __syncthreads();

    // ---- Phase 4: scatter this block's 256 rows, coalesced float4 stores ----
    const int row = blockIdx.x * BLOCK + tid;
    const int tok = x[row];                            // L1/L2-hot re-read
    reinterpret_cast<float4*>(out)[row] = Otab[tok];
}

extern "C" void kernel_launch(void* const* d_in, const int* in_sizes, int n_in,
                              void* d_out, int out_size, void* d_ws, size_t ws_size,
                              hipStream_t stream) {
    const int*   x   = (const int*)  d_in[0];
    const float* emb = (const float*)d_in[1];
    const float* Wq  = (const float*)d_in[2];
    const float* bq  = (const float*)d_in[3];
    const float* Wk  = (const float*)d_in[4];
    const float* bk  = (const float*)d_in[5];
    const float* Wv  = (const float*)d_in[6];
    const float* bv  = (const float*)d_in[7];
    float* out = (float*)d_out;

    fused_tok_attn<<<GRID, BLOCK, 0, stream>>>(x, emb, Wq, bq, Wk, bk, Wv, bv, out);
}

// Round 2
// 9.291 us; speedup vs baseline: 1.2001x; 1.2001x over previous
//
#include <hip/hip_runtime.h>

constexpr int SEQ    = 8192;
constexpr int VOCAB  = 10;
constexpr int D_EMB  = 3;
constexpr int D_HEAD = 4;
constexpr int BLOCK  = 256;
constexpr int GRID   = SEQ / BLOCK;   // 32 blocks, 1 output row per thread
constexpr int NWAVE  = BLOCK / 64;    // 4 waves
constexpr int ITERS  = SEQ / (BLOCK * 4);  // 8 int4 loads per thread

__global__ __launch_bounds__(BLOCK) void fused_tok_attn(
    const int*   __restrict__ x,
    const float* __restrict__ emb_table,
    const float* __restrict__ Wq, const float* __restrict__ bq,
    const float* __restrict__ Wk, const float* __restrict__ bk,
    const float* __restrict__ Wv, const float* __restrict__ bv,
    float*       __restrict__ out)
{
    __shared__ float qt[VOCAB][D_HEAD];
    __shared__ float kt[VOCAB][D_HEAD];
    __shared__ float vt[VOCAB][D_HEAD];
    __shared__ unsigned long long wh[NWAVE][3];   // per-wave packed counts
    __shared__ float4 Otab[VOCAB];

    const int tid = threadIdx.x;
    const int row = blockIdx.x * BLOCK + tid;

    // ---- Issue ALL global loads up front so latency overlaps everything ----
    const int tok_self = x[row];                  // needed only in phase 4
    const int4* x4 = reinterpret_cast<const int4*>(x);
    int4 tk[ITERS];
#pragma unroll
    for (int i = 0; i < ITERS; ++i) tk[i] = x4[i * BLOCK + tid];

    // ---- Phase A: q/k/v type tables, one (type,dim) pair per lane (40 lanes) ----
    if (tid < VOCAB * D_HEAD) {
        const int t = tid >> 2, d = tid & 3;
        const float e0 = emb_table[t * D_EMB + 0];
        const float e1 = emb_table[t * D_EMB + 1];
        const float e2 = emb_table[t * D_EMB + 2];
        qt[t][d] = fmaf(e0, Wq[0 * D_HEAD + d],
                   fmaf(e1, Wq[1 * D_HEAD + d],
                   fmaf(e2, Wq[2 * D_HEAD + d], bq[d])));
        kt[t][d] = fmaf(e0, Wk[0 * D_HEAD + d],
                   fmaf(e1, Wk[1 * D_HEAD + d],
                   fmaf(e2, Wk[2 * D_HEAD + d], bk[d])));
        vt[t][d] = fmaf(e0, Wv[0 * D_HEAD + d],
                   fmaf(e1, Wv[1 * D_HEAD + d],
                   fmaf(e2, Wv[2 * D_HEAD + d], bv[d])));
    }

    // ---- Phase B: packed histogram. 6-bit fields; per-thread count <= 32 < 63 ----
    unsigned long long p6 = 0ULL;
#pragma unroll
    for (int i = 0; i < ITERS; ++i) {
        p6 += 1ULL << (6 * tk[i].x);
        p6 += 1ULL << (6 * tk[i].y);
        p6 += 1ULL << (6 * tk[i].z);
        p6 += 1ULL << (6 * tk[i].w);
    }
    // widen to 16-bit fields across 3 u64s (wave sum <= 2048 per field: safe)
    unsigned long long h0 = 0, h1 = 0, h2 = 0;
#pragma unroll
    for (int t = 0; t < VOCAB; ++t) {
        const unsigned long long c = (p6 >> (6 * t)) & 63ULL;
        if ((t >> 2) == 0) h0 += c << (16 * (t & 3));
        else if ((t >> 2) == 1) h1 += c << (16 * (t & 3));
        else h2 += c << (16 * (t & 3));
    }
    // 3 independent butterfly chains, 6 levels
#pragma unroll
    for (int off = 32; off > 0; off >>= 1) {
        h0 += __shfl_down(h0, off);
        h1 += __shfl_down(h1, off);
        h2 += __shfl_down(h2, off);
    }
    if ((tid & 63) == 0) {
        const int wv = tid >> 6;
        wh[wv][0] = h0; wh[wv][1] = h1; wh[wv][2] = h2;
    }
    __syncthreads();

    // ---- Phase C: per-type softmax-attention output row (10 lanes) ----
    if (tid < VOCAB) {
        const int a = tid;
        unsigned long long g[3];
#pragma unroll
        for (int j = 0; j < 3; ++j)
            g[j] = wh[0][j] + wh[1][j] + wh[2][j] + wh[3][j];
        float cntf[VOCAB];
#pragma unroll
        for (int t = 0; t < VOCAB; ++t)
            cntf[t] = (float)((g[t >> 2] >> (16 * (t & 3))) & 0xFFFFULL);

        float s[VOCAB];
        float m = -3.0e38f;
#pragma unroll
        for (int t = 0; t < VOCAB; ++t) {
            const float sv = 0.5f * (qt[a][0] * kt[t][0] + qt[a][1] * kt[t][1] +
                                     qt[a][2] * kt[t][2] + qt[a][3] * kt[t][3]);
            s[t] = sv;
            m = fmaxf(m, sv);
        }
        float denom = 0.f, o0 = 0.f, o1 = 0.f, o2 = 0.f, o3 = 0.f;
#pragma unroll
        for (int t = 0; t < VOCAB; ++t) {
            const float w = cntf[t] * __expf(s[t] - m);   // s-m <= 0: no overflow
            denom += w;
            o0 = fmaf(w, vt[t][0], o0);
            o1 = fmaf(w, vt[t][1], o1);
            o2 = fmaf(w, vt[t][2], o2);
            o3 = fmaf(w, vt[t][3], o3);
        }
        const float inv = 1.0f / denom;
        Otab[a] = make_float4(o0 * inv, o1 * inv, o2 * inv, o3 * inv);
    }
    __syncthreads();

    // ---- Phase D: coalesced float4 store, token already in a register ----
    reinterpret_cast<float4*>(out)[row] = Otab[tok_self];
}

extern "C" void kernel_launch(void* const* d_in, const int* in_sizes, int n_in,
                              void* d_out, int out_size, void* d_ws, size_t ws_size,
                              hipStream_t stream) {
    const int*   x   = (const int*)  d_in[0];
    const float* emb = (const float*)d_in[1];
    const float* Wq  = (const float*)d_in[2];
    const float* bq  = (const float*)d_in[3];
    const float* Wk  = (const float*)d_in[4];
    const float* bk  = (const float*)d_in[5];
    const float* Wv  = (const float*)d_in[6];
    const float* bv  = (const float*)d_in[7];
    float* out = (float*)d_out;

    fused_tok_attn<<<GRID, BLOCK, 0, stream>>>(x, emb, Wq, bq, Wk, bk, Wv, bv, out);
}